// Round 23
// baseline (226.018 us; speedup 1.0000x reference)
//
#include <hip/hip_runtime.h>

// biDAF attention: S = s1 s2^T, masked softmax over t2, U = P s2.
// B=32 (from in_sizes), t1=t2=D=1024, fp32 in/out.
//
// Round-23: r22 (best 225.2 us, absmax 0.0479) + gemm1 BK=32 -> BK=64.
//  r22 counters: MfmaUtil 6.1%, VALUBusy 6.2% -- the gemm1 loop is nearly
//  pure barrier overhead (16 MFMA ~ 78 cy between 2 full barrier drains,
//  x16 steps). BK=64: stage both 32-chunks per step (2 planes x [128][72]
//  u16 = 36 KB, stride 144 B = 9x16B aligned, <=2-way banks), 32 MFMA per
//  step, 8 steps -> HALF the barriers. Prefetch pA[8]/pB[8] float4,
//  statically indexed (proven no-spill form). Occupancy is work-limited
//  (1.6 waves/SIMD) so the VGPR increase shouldn't cut residency.
// Numerics unchanged from r22: QK^T = ah*bh fp16 (1 MFMA), PV = Ph*Vh fp16,
// S partials fp32. absmax 0.04785 vs threshold 0.0994.

typedef __attribute__((ext_vector_type(8))) _Float16 f16x8;
typedef __attribute__((ext_vector_type(8))) unsigned short u16x8;
typedef __attribute__((ext_vector_type(4))) float f32x4;
typedef unsigned short u16;

constexpr int T1 = 1024;
constexpr int T2 = 1024;
constexpr int DD = 1024;
constexpr float NEGV = -1e30f;
constexpr int RS = 72;           // u16 row stride for BK=64 tiles (144 B)

__device__ __forceinline__ u16 f16b(float x) {          // fp32 -> fp16 (RN), bits
    union { _Float16 f; u16 u; } cv;
    cv.f = (_Float16)x;
    return cv.u;
}

__device__ __forceinline__ void cvtf16x8(const float4& a, const float4& b, u16x8& h) {
    h[0] = f16b(a.x); h[1] = f16b(a.y); h[2] = f16b(a.z); h[3] = f16b(a.w);
    h[4] = f16b(b.x); h[5] = f16b(b.y); h[6] = f16b(b.z); h[7] = f16b(b.w);
}

// ---------------- fused k0+k1: gemm1 (BK=64) K-split blocks, then conv backfill ----------------
__global__ __launch_bounds__(256, 2)
void gemm1_conv(const float* __restrict__ s1, const float* __restrict__ s2,
                const int* __restrict__ l1, const int* __restrict__ l2,
                float* __restrict__ SPa, float* __restrict__ SPb,
                u16* __restrict__ s2th, int ng1)
{
    __shared__ __align__(16) u16 sBuf[2 * 128 * RS];     // 36 KB, dual-use

    int bid = (int)blockIdx.x;
    if (bid >= ng1) {
        // ======== conv path: s2 -> transposed fp16-RN hi plane ========
        int cid = bid - ng1;
        int b = cid >> 8;
        int j0 = ((cid >> 4) & 15) * 64;
        int d0 = (cid & 15) * 64;
        if (j0 >= l2[b]) return;             // cols never read downstream
        float (*tile)[65] = (float(*)[65])sBuf;          // 16.6 KB < 36 KB
        int t = (int)threadIdx.x;
        const float* src = s2 + ((size_t)b * T2 + j0) * DD + d0;
        #pragma unroll
        for (int rr = 0; rr < 4; ++rr) {
            int row = (t >> 4) + rr * 16, c4 = (t & 15) * 4;
            float4 v = *(const float4*)&src[(size_t)row * DD + c4];
            tile[row][c4 + 0] = v.x; tile[row][c4 + 1] = v.y;
            tile[row][c4 + 2] = v.z; tile[row][c4 + 3] = v.w;
        }
        __syncthreads();
        #pragma unroll
        for (int rr = 0; rr < 4; ++rr) {
            int d = (t >> 4) + rr * 16, j4 = (t & 15) * 4;
            ushort4 h;
            h.x = f16b(tile[j4 + 0][d]);
            h.y = f16b(tile[j4 + 1][d]);
            h.z = f16b(tile[j4 + 2][d]);
            h.w = f16b(tile[j4 + 3][d]);
            size_t o = ((size_t)b * DD + d0 + d) * T2 + j0 + j4;
            *(ushort4*)&s2th[o] = h;
        }
        return;
    }

    // ======== gemm1 path: S = ah*bh (pure fp16), K-split, BK=64 ========
    u16* sAh = sBuf;
    u16* sBh = sBuf + 128 * RS;

    int idx = bid;
    int batch = idx >> 7;
    int rt = (idx >> 4) & 7, ct = (idx >> 1) & 7, kp = idx & 1;
    int row0 = rt * 128, col0 = ct * 128;
    if (row0 >= l1[batch] || col0 >= l2[batch]) return;

    int t = (int)threadIdx.x;
    int lrow = t >> 2, lslot = t & 3;       // thread covers floats [lslot*8, lslot*8+8) per chunk
    int w = t >> 6, lane = t & 63, lr = lane & 15, lg = lane >> 4;
    int wr = (w >> 1) * 64, wc = (w & 1) * 64;

    const float* As = s1 + ((size_t)batch * T1 + row0) * DD + kp * 512;
    const float* Bs = s2 + ((size_t)batch * T2 + col0) * DD + kp * 512;
    float* SP = kp ? SPb : SPa;
    float* Cs = SP + ((size_t)batch * T1 + row0) * (size_t)T2 + col0;

    f32x4 acc[4][4];
    #pragma unroll
    for (int i = 0; i < 4; ++i)
        #pragma unroll
        for (int j = 0; j < 4; ++j) acc[i][j] = (f32x4)0.f;

    // prefetch regs: [rr*4 + ch*2 + c], rr=row-half, ch=k-chunk(32), c=float4-half
    float4 pA[8], pB[8];
    #pragma unroll
    for (int rr = 0; rr < 2; ++rr)
        #pragma unroll
        for (int ch = 0; ch < 2; ++ch)
            #pragma unroll
            for (int c = 0; c < 2; ++c) {
                size_t off = (size_t)(lrow + rr * 64) * DD + ch * 32 + lslot * 8 + c * 4;
                pA[rr * 4 + ch * 2 + c] = *(const float4*)&As[off];
                pB[rr * 4 + ch * 2 + c] = *(const float4*)&Bs[off];
            }

    for (int k0 = 0; k0 < 512; k0 += 64) {
        __syncthreads();
        #pragma unroll
        for (int rr = 0; rr < 2; ++rr)
            #pragma unroll
            for (int ch = 0; ch < 2; ++ch) {
                int o = (lrow + rr * 64) * RS + ch * 32 + lslot * 8;  // 16B store
                u16x8 h;
                cvtf16x8(pA[rr * 4 + ch * 2], pA[rr * 4 + ch * 2 + 1], h);
                *(u16x8*)&sAh[o] = h;
                cvtf16x8(pB[rr * 4 + ch * 2], pB[rr * 4 + ch * 2 + 1], h);
                *(u16x8*)&sBh[o] = h;
            }
        if (k0 + 64 < 512) {                 // prefetch next 64-chunk under MFMA
            int kn = k0 + 64;
            #pragma unroll
            for (int rr = 0; rr < 2; ++rr)
                #pragma unroll
                for (int ch = 0; ch < 2; ++ch)
                    #pragma unroll
                    for (int c = 0; c < 2; ++c) {
                        size_t off = (size_t)(lrow + rr * 64) * DD + kn + ch * 32 + lslot * 8 + c * 4;
                        pA[rr * 4 + ch * 2 + c] = *(const float4*)&As[off];
                        pB[rr * 4 + ch * 2 + c] = *(const float4*)&Bs[off];
                    }
        }
        __syncthreads();
        #pragma unroll
        for (int ch = 0; ch < 2; ++ch) {
            f16x8 ah[4];
            #pragma unroll
            for (int i = 0; i < 4; ++i) {
                int o = (wr + i * 16 + lr) * RS + ch * 32 + lg * 8;
                ah[i] = *(const f16x8*)&sAh[o];
            }
            #pragma unroll
            for (int j = 0; j < 4; ++j) {
                int o = (wc + j * 16 + lr) * RS + ch * 32 + lg * 8;
                f16x8 bh = *(const f16x8*)&sBh[o];
                #pragma unroll
                for (int i = 0; i < 4; ++i)
                    acc[i][j] = __builtin_amdgcn_mfma_f32_16x16x32_f16(ah[i], bh, acc[i][j], 0, 0, 0);
            }
        }
    }
    #pragma unroll
    for (int i = 0; i < 4; ++i)
        #pragma unroll
        for (int j = 0; j < 4; ++j)
            #pragma unroll
            for (int reg = 0; reg < 4; ++reg)
                Cs[(size_t)(wr + i * 16 + 4 * lg + reg) * T2 + wc + j * 16 + lr] = acc[i][j][reg];
}

// ------- k2: masked softmax (l2-bounded chunks) | dead-tile zerofill backfill -------
__global__ __launch_bounds__(256)
void softmax_rows(float* __restrict__ SPa, const float* __restrict__ SPb,
                  int dual, const int* __restrict__ l1, const int* __restrict__ l2,
                  float* __restrict__ out, int ngs)
{
    int bid = (int)blockIdx.x;
    if (bid >= ngs) {
        // ======== zerofill path: dead output q-tiles (row0 >= l1) ========
        int zid = bid - ngs;
        int b = zid >> 6;
        int rt = (zid >> 3) & 7, ct = zid & 7;
        int row0 = rt * 128;
        if (row0 < l1[b]) return;            // live tile: gemm2 writes it
        float* Co = out + ((size_t)b * T1 + row0) * (size_t)DD + ct * 128;
        int t = (int)threadIdx.x;
        float4 z = make_float4(0.f, 0.f, 0.f, 0.f);
        #pragma unroll
        for (int rr = 0; rr < 2; ++rr) {
            int row = (t >> 2) + rr * 64;
            #pragma unroll
            for (int ss = 0; ss < 8; ++ss)
                *(float4*)&Co[(size_t)row * DD + ((t & 3) + ss * 4) * 4] = z;
        }
        return;
    }

    int batch = bid >> 5;
    int row0 = (bid & 31) * 32;
    int l1v = l1[batch], l2v = l2[batch];
    if (row0 >= l1v) return;
    int w = (int)threadIdx.x >> 6, lane = (int)threadIdx.x & 63;

    for (int i = 0; i < 8; ++i) {
        int r = row0 + w * 8 + i;
        if (r >= l1v) continue;                    // wave-uniform
        size_t roff = ((size_t)batch * T1 + r) * (size_t)T2;
        float* rowa = SPa + roff;
        const float* rowb = SPb + roff;
        float x[16];
        float m = NEGV;
        #pragma unroll
        for (int s = 0; s < 4; ++s) {
            if (s * 256 < l2v) {                   // wave-uniform: skip masked chunks
                float4 va = *(const float4*)&rowa[s * 256 + lane * 4];
                if (dual) {
                    float4 vb = *(const float4*)&rowb[s * 256 + lane * 4];
                    va.x += vb.x; va.y += vb.y; va.z += vb.z; va.w += vb.w;
                }
                float xs[4] = {va.x, va.y, va.z, va.w};
                #pragma unroll
                for (int e = 0; e < 4; ++e) {
                    int j = s * 256 + lane * 4 + e;
                    float val = (j < l2v) ? xs[e] : NEGV;
                    x[s * 4 + e] = val;
                    m = fmaxf(m, val);
                }
            }
        }
        #pragma unroll
        for (int off = 32; off >= 1; off >>= 1) m = fmaxf(m, __shfl_xor(m, off));
        float sum = 0.f;
        #pragma unroll
        for (int s = 0; s < 4; ++s) {
            if (s * 256 < l2v) {
                #pragma unroll
                for (int e = 0; e < 4; ++e) {
                    float ev = __expf(x[s * 4 + e] - m);   // masked -> exp(-huge)=0
                    x[s * 4 + e] = ev;
                    sum += ev;
                }
            }
        }
        #pragma unroll
        for (int off = 32; off >= 1; off >>= 1) sum += __shfl_xor(sum, off);
        float inv = 1.f / sum;                     // l2>=1 -> sum>=1
        u16* hi = (u16*)rowa;                      // P-hi: bytes [0,2048)
        #pragma unroll
        for (int s = 0; s < 4; ++s) {
            if (s * 256 < l2v) {                   // chunks beyond never read by gemm2
                ushort4 h;
                h.x = f16b(x[s * 4 + 0] * inv);
                h.y = f16b(x[s * 4 + 1] * inv);
                h.z = f16b(x[s * 4 + 2] * inv);
                h.w = f16b(x[s * 4 + 3] * inv);
                *(ushort4*)&hi[s * 256 + lane * 4] = h;
            }
        }
    }
}

// ---------------- k3: U = Ph x Vh (fp16, 1 MFMA; dead tiles pre-zeroed) ----------------
__global__ __launch_bounds__(256, 2)
void gemm2_pv(const float* __restrict__ SP, const u16* __restrict__ s2th,
              const int* __restrict__ l1, const int* __restrict__ l2,
              float* __restrict__ out)
{
    __shared__ u16 sAh[128 * 40], sBh[128 * 40];

    int idx = (int)blockIdx.x;              // natural order
    int batch = idx >> 6;
    int rt = (idx >> 3) & 7, ct = idx & 7;
    int row0 = rt * 128, col0 = ct * 128;   // q-rows, d-cols
    int l1v = l1[batch], l2v = l2[batch];
    if (row0 >= l1v) return;                // dead tile: zero-filled in dispatch 2

    int t = (int)threadIdx.x;
    float* Co = out + ((size_t)batch * T1 + row0) * (size_t)DD + col0;

    int lrow = t >> 2, lslot = t & 3;       // thread covers u16 [lslot*8, lslot*8+8)
    int w = t >> 6, lane = t & 63, lr = lane & 15, lg = lane >> 4;
    int wr = (w >> 1) * 64, wc = (w & 1) * 64;

    const u16* Pb = (const u16*)SP;         // row q: hi at q*2048
    size_t arow = ((size_t)batch * T1 + row0);
    const u16* Bh_g = s2th + ((size_t)batch * DD + col0) * (size_t)T2;

    f32x4 acc[4][4];
    #pragma unroll
    for (int i = 0; i < 4; ++i)
        #pragma unroll
        for (int j = 0; j < 4; ++j) acc[i][j] = (f32x4)0.f;

    int nk = (l2v + 31) >> 5;
    ushort4 pAh[4], pBh[4];                 // [rr*2+ss]: u16 lslot*8 + ss*4 (contiguous)
    #pragma unroll
    for (int rr = 0; rr < 2; ++rr)
        #pragma unroll
        for (int ss = 0; ss < 2; ++ss) {
            int q = lrow + rr * 64, s4 = lslot * 8 + ss * 4;
            pAh[rr * 2 + ss] = *(const ushort4*)&Pb[(arow + q) * 2048 + s4];
            pBh[rr * 2 + ss] = *(const ushort4*)&Bh_g[(size_t)q * T2 + s4];
        }

    for (int kk = 0; kk < nk; ++kk) {
        __syncthreads();
        #pragma unroll
        for (int rr = 0; rr < 2; ++rr)
            #pragma unroll
            for (int ss = 0; ss < 2; ++ss) {
                int o = (lrow + rr * 64) * 40 + lslot * 8 + ss * 4;  // adjacent 8B pair
                *(ushort4*)&sAh[o] = pAh[rr * 2 + ss];
                *(ushort4*)&sBh[o] = pBh[rr * 2 + ss];
            }
        if (kk + 1 < nk) {
            int kn = (kk + 1) * 32;
            #pragma unroll
            for (int rr = 0; rr < 2; ++rr)
                #pragma unroll
                for (int ss = 0; ss < 2; ++ss) {
                    int q = lrow + rr * 64, s4 = kn + lslot * 8 + ss * 4;
                    pAh[rr * 2 + ss] = *(const ushort4*)&Pb[(arow + q) * 2048 + s4];
                    pBh[rr * 2 + ss] = *(const ushort4*)&Bh_g[(size_t)q * T2 + s4];
                }
        }
        __syncthreads();
        f16x8 ph[4];
        #pragma unroll
        for (int i = 0; i < 4; ++i) {
            int o = (wr + i * 16 + lr) * 40 + lg * 8;
            ph[i] = *(const f16x8*)&sAh[o];
        }
        #pragma unroll
        for (int j = 0; j < 4; ++j) {
            int o = (wc + j * 16 + lr) * 40 + lg * 8;
            f16x8 vh = *(const f16x8*)&sBh[o];
            #pragma unroll
            for (int i = 0; i < 4; ++i)
                acc[i][j] = __builtin_amdgcn_mfma_f32_16x16x32_f16(ph[i], vh, acc[i][j], 0, 0, 0);
        }
    }
    #pragma unroll
    for (int i = 0; i < 4; ++i)
        #pragma unroll
        for (int reg = 0; reg < 4; ++reg) {
            int row = wr + i * 16 + 4 * lg + reg;
            bool valid = (row0 + row) < l1v;
            #pragma unroll
            for (int j = 0; j < 4; ++j)
                Co[(size_t)row * DD + wc + j * 16 + lr] = valid ? acc[i][j][reg] : 0.f;
        }
}

// ======= fallback path kernels (ws < 320 MiB; never exercised on this rig) =======
__global__ __launch_bounds__(256)
void conv_transpose(const float* __restrict__ s2, const int* __restrict__ l2,
                    u16* __restrict__ s2th)
{
    __shared__ float tile[64][65];
    int b = blockIdx.z, j0 = blockIdx.y * 64, d0 = blockIdx.x * 64;
    if (j0 >= l2[b]) return;
    int t = threadIdx.x;
    const float* src = s2 + ((size_t)b * T2 + j0) * DD + d0;
    #pragma unroll
    for (int rr = 0; rr < 4; ++rr) {
        int row = (t >> 4) + rr * 16, c4 = (t & 15) * 4;
        float4 v = *(const float4*)&src[(size_t)row * DD + c4];
        tile[row][c4 + 0] = v.x; tile[row][c4 + 1] = v.y;
        tile[row][c4 + 2] = v.z; tile[row][c4 + 3] = v.w;
    }
    __syncthreads();
    #pragma unroll
    for (int rr = 0; rr < 4; ++rr) {
        int d = (t >> 4) + rr * 16, j4 = (t & 15) * 4;
        ushort4 h;
        h.x = f16b(tile[j4 + 0][d]);
        h.y = f16b(tile[j4 + 1][d]);
        h.z = f16b(tile[j4 + 2][d]);
        h.w = f16b(tile[j4 + 3][d]);
        size_t o = ((size_t)b * DD + d0 + d) * T2 + j0 + j4;
        *(ushort4*)&s2th[o] = h;
    }
}

__global__ __launch_bounds__(256, 2)
void gemm1_qk(const float* __restrict__ s1, const int* __restrict__ l1,
              const float* __restrict__ s2, const int* __restrict__ l2,
              float* __restrict__ SP)
{
    __shared__ u16 sAh[128 * 40], sBh[128 * 40];

    int idx = (int)blockIdx.x;
    int batch = idx >> 6;
    int rt = (idx >> 3) & 7, ct = idx & 7;
    int row0 = rt * 128, col0 = ct * 128;
    if (row0 >= l1[batch] || col0 >= l2[batch]) return;

    int t = (int)threadIdx.x;
    int lrow = t >> 2, lslot = t & 3;
    int w = t >> 6, lane = t & 63, lr = lane & 15, lg = lane >> 4;
    int wr = (w >> 1) * 64, wc = (w & 1) * 64;

    const float* As = s1 + ((size_t)batch * T1 + row0) * DD;
    const float* Bs = s2 + ((size_t)batch * T2 + col0) * DD;
    float* Cs = SP + ((size_t)batch * T1 + row0) * (size_t)T2 + col0;

    f32x4 acc[4][4];
    #pragma unroll
    for (int i = 0; i < 4; ++i)
        #pragma unroll
        for (int j = 0; j < 4; ++j) acc[i][j] = (f32x4)0.f;

    float4 pA[4], pB[4];
    #pragma unroll
    for (int rr = 0; rr < 2; ++rr)
        #pragma unroll
        for (int c = 0; c < 2; ++c) {
            pA[rr * 2 + c] = *(const float4*)&As[(size_t)(lrow + rr * 64) * DD + lslot * 8 + c * 4];
            pB[rr * 2 + c] = *(const float4*)&Bs[(size_t)(lrow + rr * 64) * DD + lslot * 8 + c * 4];
        }

    for (int k0 = 0; k0 < DD; k0 += 32) {
        __syncthreads();
        #pragma unroll
        for (int rr = 0; rr < 2; ++rr) {
            int o = (lrow + rr * 64) * 40 + lslot * 8;
            u16x8 h;
            cvtf16x8(pA[rr * 2], pA[rr * 2 + 1], h);
            *(u16x8*)&sAh[o] = h;
            cvtf16x8(pB[rr * 2], pB[rr * 2 + 1], h);
            *(u16x8*)&sBh[o] = h;
        }
        if (k0 + 32 < DD) {
            int kn = k0 + 32;
            #pragma unroll
            for (int rr = 0; rr < 2; ++rr)
                #pragma unroll
                for (int c = 0; c < 2; ++c) {
                    pA[rr * 2 + c] = *(const float4*)&As[(size_t)(lrow + rr * 64) * DD + kn + lslot * 8 + c * 4];
                    pB[rr * 2 + c] = *(const float4*)&Bs[(size_t)(lrow + rr * 64) * DD + kn + lslot * 8 + c * 4];
                }
        }
        __syncthreads();
        f16x8 ah[4];
        #pragma unroll
        for (int i = 0; i < 4; ++i) {
            int o = (wr + i * 16 + lr) * 40 + lg * 8;
            ah[i] = *(const f16x8*)&sAh[o];
        }
        #pragma unroll
        for (int j = 0; j < 4; ++j) {
            int o = (wc + j * 16 + lr) * 40 + lg * 8;
            f16x8 bh = *(const f16x8*)&sBh[o];
            #pragma unroll
            for (int i = 0; i < 4; ++i)
                acc[i][j] = __builtin_amdgcn_mfma_f32_16x16x32_f16(ah[i], bh, acc[i][j], 0, 0, 0);
        }
    }
    #pragma unroll
    for (int i = 0; i < 4; ++i)
        #pragma unroll
        for (int j = 0; j < 4; ++j)
            #pragma unroll
            for (int reg = 0; reg < 4; ++reg)
                Cs[(size_t)(wr + i * 16 + 4 * lg + reg) * T2 + wc + j * 16 + lr] = acc[i][j][reg];
}

extern "C" void kernel_launch(void* const* d_in, const int* in_sizes, int n_in,
                              void* d_out, int out_size, void* d_ws, size_t ws_size,
                              hipStream_t stream)
{
    const float* s1 = (const float*)d_in[0];
    const int* l1 = (const int*)d_in[1];
    const float* s2 = (const float*)d_in[2];
    const int* l2 = (const int*)d_in[3];
    float* outp = (float*)d_out;

    int B = in_sizes[1];
    size_t elems = (size_t)B * T2 * DD;
    size_t sp_bytes = elems * sizeof(float);        // 128 MiB @B=32
    size_t plane = elems * sizeof(u16);             // 64 MiB

    if (ws_size >= 2 * sp_bytes + plane) {
        // main: fused {gemm1 fp16 BK=64 K-split + conv}, {softmax | zerofill}, PV
        char* p = (char*)d_ws;
        float* SPa = (float*)p;             p += sp_bytes;
        float* SPb = (float*)p;             p += sp_bytes;
        u16* s2th = (u16*)p;
        int ng1 = B * 128;
        int ngc = B * 256;                  // (T2/64)*(DD/64) per batch
        int ngs = B * 32;                   // softmax row-tiles
        int ngz = B * 64;                   // output q-tiles (zerofill)
        gemm1_conv<<<dim3(ng1 + ngc), 256, 0, stream>>>(s1, s2, l1, l2, SPa, SPb, s2th, ng1);
        softmax_rows<<<dim3(ngs + ngz), 256, 0, stream>>>(SPa, SPb, 1, l1, l2, outp, ngs);
        gemm2_pv<<<dim3(B * 64), 256, 0, stream>>>(SPa, s2th, l1, l2, outp);
    } else {
        // fallback: full-K fp16 gemm1 (BK=32), separate conv; zerofill rides softmax
        float* SPa = (float*)d_ws;
        u16* s2th = (u16*)((char*)d_ws + sp_bytes);
        int ngs = B * 32, ngz = B * 64;
        conv_transpose<<<dim3(DD / 64, T2 / 64, B), 256, 0, stream>>>(s2, l2, s2th);
        gemm1_qk<<<dim3(B * 64), 256, 0, stream>>>(s1, l1, s2, l2, SPa);
        softmax_rows<<<dim3(ngs + ngz), 256, 0, stream>>>(SPa, SPa, 0, l1, l2, outp, ngs);
        gemm2_pv<<<dim3(B * 64), 256, 0, stream>>>(SPa, s2th, l1, l2, outp);
    }
}

// Round 24
// 222.631 us; speedup vs baseline: 1.0152x; 1.0152x over previous
//
#include <hip/hip_runtime.h>

// biDAF attention: S = s1 s2^T, masked softmax over t2, U = P s2.
// B=32 (from in_sizes), t1=t2=D=1024, fp32 in/out.
//
// Round-24: r22 structure (best 225.2, absmax 0.0479) + fp16 S-PARTIALS.
//  gemm1_conv is latency-bound at 2.65 TB/s effective (42% of achievable);
//  the reducible quantity is bytes. SPa/SPb stored as fp16 u16 planes:
//  gemm1 S-writes 83->41 MB, softmax reads halve (-124 MB).
//  Error: per-partial fp16 quantization ~0.02 (ulp 0.0625 @ |S|<128), two
//  partials RSS ~0.03 pre-exp; measured softmax cancellation (r18/r22:
//  actual increments 3-4x under worst case) -> predicted absmax 0.055-0.075
//  vs threshold 0.0994. Revert to r22 if fail.
// Numerics otherwise: QK^T = ah*bh fp16 (1 MFMA), PV = Ph*Vh fp16 (1 MFMA).
// Structure: BK=32 2-barrier template (r22, measured best); fused
// {gemm1|conv}, {softmax(l2-bounded)|zerofill}, gemm2 dead-tile early-return.

typedef __attribute__((ext_vector_type(8))) _Float16 f16x8;
typedef __attribute__((ext_vector_type(8))) unsigned short u16x8;
typedef __attribute__((ext_vector_type(4))) float f32x4;
typedef unsigned short u16;

constexpr int T1 = 1024;
constexpr int T2 = 1024;
constexpr int DD = 1024;
constexpr float NEGV = -1e30f;

__device__ __forceinline__ u16 f16b(float x) {          // fp32 -> fp16 (RN), bits
    union { _Float16 f; u16 u; } cv;
    cv.f = (_Float16)x;
    return cv.u;
}

__device__ __forceinline__ float f16tof(u16 b) {        // fp16 bits -> fp32
    union { _Float16 f; u16 u; } cv;
    cv.u = b;
    return (float)cv.f;
}

__device__ __forceinline__ void cvtf16x8(const float4& a, const float4& b, u16x8& h) {
    h[0] = f16b(a.x); h[1] = f16b(a.y); h[2] = f16b(a.z); h[3] = f16b(a.w);
    h[4] = f16b(b.x); h[5] = f16b(b.y); h[6] = f16b(b.z); h[7] = f16b(b.w);
}

// ---------------- fused k0+k1: gemm1 K-split blocks, then conv backfill ----------------
__global__ __launch_bounds__(256, 2)
void gemm1_conv(const float* __restrict__ s1, const float* __restrict__ s2,
                const int* __restrict__ l1, const int* __restrict__ l2,
                u16* __restrict__ SPa, u16* __restrict__ SPb,
                u16* __restrict__ s2th, int ng1)
{
    __shared__ __align__(16) u16 sBuf[2 * 128 * 40];     // 20 KB, dual-use

    int bid = (int)blockIdx.x;
    if (bid >= ng1) {
        // ======== conv path: s2 -> transposed fp16-RN hi plane ========
        int cid = bid - ng1;
        int b = cid >> 8;
        int j0 = ((cid >> 4) & 15) * 64;
        int d0 = (cid & 15) * 64;
        if (j0 >= l2[b]) return;             // cols never read downstream
        float (*tile)[65] = (float(*)[65])sBuf;          // 16.6 KB < 20 KB
        int t = (int)threadIdx.x;
        const float* src = s2 + ((size_t)b * T2 + j0) * DD + d0;
        #pragma unroll
        for (int rr = 0; rr < 4; ++rr) {
            int row = (t >> 4) + rr * 16, c4 = (t & 15) * 4;
            float4 v = *(const float4*)&src[(size_t)row * DD + c4];
            tile[row][c4 + 0] = v.x; tile[row][c4 + 1] = v.y;
            tile[row][c4 + 2] = v.z; tile[row][c4 + 3] = v.w;
        }
        __syncthreads();
        #pragma unroll
        for (int rr = 0; rr < 4; ++rr) {
            int d = (t >> 4) + rr * 16, j4 = (t & 15) * 4;
            ushort4 h;
            h.x = f16b(tile[j4 + 0][d]);
            h.y = f16b(tile[j4 + 1][d]);
            h.z = f16b(tile[j4 + 2][d]);
            h.w = f16b(tile[j4 + 3][d]);
            size_t o = ((size_t)b * DD + d0 + d) * T2 + j0 + j4;
            *(ushort4*)&s2th[o] = h;
        }
        return;
    }

    // ======== gemm1 path: S = ah*bh (pure fp16, 1 MFMA), K-split, fp16 S-out ========
    u16* sAh = sBuf;
    u16* sBh = sBuf + 128 * 40;

    int idx = bid;
    int batch = idx >> 7;
    int rt = (idx >> 4) & 7, ct = (idx >> 1) & 7, kp = idx & 1;
    int row0 = rt * 128, col0 = ct * 128;
    if (row0 >= l1[batch] || col0 >= l2[batch]) return;

    int t = (int)threadIdx.x;
    int lrow = t >> 2, lslot = t & 3;       // thread covers floats [lslot*8, lslot*8+8)
    int w = t >> 6, lane = t & 63, lr = lane & 15, lg = lane >> 4;
    int wr = (w >> 1) * 64, wc = (w & 1) * 64;

    const float* As = s1 + ((size_t)batch * T1 + row0) * DD + kp * 512;
    const float* Bs = s2 + ((size_t)batch * T2 + col0) * DD + kp * 512;
    u16* SP = kp ? SPb : SPa;
    u16* Cs = SP + ((size_t)batch * T1 + row0) * (size_t)T2 + col0;

    f32x4 acc[4][4];
    #pragma unroll
    for (int i = 0; i < 4; ++i)
        #pragma unroll
        for (int j = 0; j < 4; ++j) acc[i][j] = (f32x4)0.f;

    float4 pA[4], pB[4];                    // [rr*2+c]: floats lslot*8 + c*4 (contiguous)
    #pragma unroll
    for (int rr = 0; rr < 2; ++rr)
        #pragma unroll
        for (int c = 0; c < 2; ++c) {
            pA[rr * 2 + c] = *(const float4*)&As[(size_t)(lrow + rr * 64) * DD + lslot * 8 + c * 4];
            pB[rr * 2 + c] = *(const float4*)&Bs[(size_t)(lrow + rr * 64) * DD + lslot * 8 + c * 4];
        }

    for (int k0 = 0; k0 < 512; k0 += 32) {
        __syncthreads();
        #pragma unroll
        for (int rr = 0; rr < 2; ++rr) {
            int o = (lrow + rr * 64) * 40 + lslot * 8;   // 16B store, 16B-aligned
            u16x8 h;
            cvtf16x8(pA[rr * 2], pA[rr * 2 + 1], h);
            *(u16x8*)&sAh[o] = h;
            cvtf16x8(pB[rr * 2], pB[rr * 2 + 1], h);
            *(u16x8*)&sBh[o] = h;
        }
        if (k0 + 32 < 512) {                 // prefetch next chunk under MFMA
            int kn = k0 + 32;
            #pragma unroll
            for (int rr = 0; rr < 2; ++rr)
                #pragma unroll
                for (int c = 0; c < 2; ++c) {
                    pA[rr * 2 + c] = *(const float4*)&As[(size_t)(lrow + rr * 64) * DD + kn + lslot * 8 + c * 4];
                    pB[rr * 2 + c] = *(const float4*)&Bs[(size_t)(lrow + rr * 64) * DD + kn + lslot * 8 + c * 4];
                }
        }
        __syncthreads();
        f16x8 ah[4];
        #pragma unroll
        for (int i = 0; i < 4; ++i) {
            int o = (wr + i * 16 + lr) * 40 + lg * 8;
            ah[i] = *(const f16x8*)&sAh[o];
        }
        #pragma unroll
        for (int j = 0; j < 4; ++j) {
            int o = (wc + j * 16 + lr) * 40 + lg * 8;
            f16x8 bh = *(const f16x8*)&sBh[o];
            #pragma unroll
            for (int i = 0; i < 4; ++i)
                acc[i][j] = __builtin_amdgcn_mfma_f32_16x16x32_f16(ah[i], bh, acc[i][j], 0, 0, 0);
        }
    }
    #pragma unroll
    for (int i = 0; i < 4; ++i)
        #pragma unroll
        for (int j = 0; j < 4; ++j)
            #pragma unroll
            for (int reg = 0; reg < 4; ++reg)
                Cs[(size_t)(wr + i * 16 + 4 * lg + reg) * T2 + wc + j * 16 + lr] =
                    f16b(acc[i][j][reg]);
}

// ------- k2: masked softmax (fp16 S-in, l2-bounded) | dead-tile zerofill -------
__global__ __launch_bounds__(256)
void softmax_rows(u16* __restrict__ SPa, const u16* __restrict__ SPb,
                  int dual, const int* __restrict__ l1, const int* __restrict__ l2,
                  float* __restrict__ out, int ngs)
{
    int bid = (int)blockIdx.x;
    if (bid >= ngs) {
        // ======== zerofill path: dead output q-tiles (row0 >= l1) ========
        int zid = bid - ngs;
        int b = zid >> 6;
        int rt = (zid >> 3) & 7, ct = zid & 7;
        int row0 = rt * 128;
        if (row0 < l1[b]) return;            // live tile: gemm2 writes it
        float* Co = out + ((size_t)b * T1 + row0) * (size_t)DD + ct * 128;
        int t = (int)threadIdx.x;
        float4 z = make_float4(0.f, 0.f, 0.f, 0.f);
        #pragma unroll
        for (int rr = 0; rr < 2; ++rr) {
            int row = (t >> 2) + rr * 64;
            #pragma unroll
            for (int ss = 0; ss < 8; ++ss)
                *(float4*)&Co[(size_t)row * DD + ((t & 3) + ss * 4) * 4] = z;
        }
        return;
    }

    int batch = bid >> 5;
    int row0 = (bid & 31) * 32;
    int l1v = l1[batch], l2v = l2[batch];
    if (row0 >= l1v) return;
    int w = (int)threadIdx.x >> 6, lane = (int)threadIdx.x & 63;

    for (int i = 0; i < 8; ++i) {
        int r = row0 + w * 8 + i;
        if (r >= l1v) continue;                    // wave-uniform
        size_t roff = ((size_t)batch * T1 + r) * (size_t)T2;   // u16 units
        u16* rowa = SPa + roff;
        const u16* rowb = SPb + roff;
        float x[16];
        float m = NEGV;
        #pragma unroll
        for (int s = 0; s < 4; ++s) {
            if (s * 256 < l2v) {                   // wave-uniform: skip masked chunks
                ushort4 va = *(const ushort4*)&rowa[s * 256 + lane * 4];
                float xs[4] = {f16tof(va.x), f16tof(va.y), f16tof(va.z), f16tof(va.w)};
                if (dual) {
                    ushort4 vb = *(const ushort4*)&rowb[s * 256 + lane * 4];
                    xs[0] += f16tof(vb.x); xs[1] += f16tof(vb.y);
                    xs[2] += f16tof(vb.z); xs[3] += f16tof(vb.w);
                }
                #pragma unroll
                for (int e = 0; e < 4; ++e) {
                    int j = s * 256 + lane * 4 + e;
                    float val = (j < l2v) ? xs[e] : NEGV;
                    x[s * 4 + e] = val;
                    m = fmaxf(m, val);
                }
            }
        }
        #pragma unroll
        for (int off = 32; off >= 1; off >>= 1) m = fmaxf(m, __shfl_xor(m, off));
        float sum = 0.f;
        #pragma unroll
        for (int s = 0; s < 4; ++s) {
            if (s * 256 < l2v) {
                #pragma unroll
                for (int e = 0; e < 4; ++e) {
                    float ev = __expf(x[s * 4 + e] - m);   // masked -> exp(-huge)=0
                    x[s * 4 + e] = ev;
                    sum += ev;
                }
            }
        }
        #pragma unroll
        for (int off = 32; off >= 1; off >>= 1) sum += __shfl_xor(sum, off);
        float inv = 1.f / sum;                     // l2>=1 -> sum>=1
        #pragma unroll
        for (int s = 0; s < 4; ++s) {
            if (s * 256 < l2v) {                   // chunks beyond never read by gemm2
                ushort4 h;
                h.x = f16b(x[s * 4 + 0] * inv);
                h.y = f16b(x[s * 4 + 1] * inv);
                h.z = f16b(x[s * 4 + 2] * inv);
                h.w = f16b(x[s * 4 + 3] * inv);
                *(ushort4*)&rowa[s * 256 + lane * 4] = h;  // P in place
            }
        }
    }
}

// ---------------- k3: U = Ph x Vh (fp16, 1 MFMA; dead tiles pre-zeroed) ----------------
__global__ __launch_bounds__(256, 2)
void gemm2_pv(const u16* __restrict__ SP, const u16* __restrict__ s2th,
              const int* __restrict__ l1, const int* __restrict__ l2,
              float* __restrict__ out)
{
    __shared__ u16 sAh[128 * 40], sBh[128 * 40];

    int idx = (int)blockIdx.x;              // natural order
    int batch = idx >> 6;
    int rt = (idx >> 3) & 7, ct = idx & 7;
    int row0 = rt * 128, col0 = ct * 128;   // q-rows, d-cols
    int l1v = l1[batch], l2v = l2[batch];
    if (row0 >= l1v) return;                // dead tile: zero-filled in dispatch 2

    int t = (int)threadIdx.x;
    float* Co = out + ((size_t)batch * T1 + row0) * (size_t)DD + col0;

    int lrow = t >> 2, lslot = t & 3;       // thread covers u16 [lslot*8, lslot*8+8)
    int w = t >> 6, lane = t & 63, lr = lane & 15, lg = lane >> 4;
    int wr = (w >> 1) * 64, wc = (w & 1) * 64;

    const u16* Pb = SP;                     // P row q at q*1024 (u16 plane)
    size_t arow = ((size_t)batch * T1 + row0);
    const u16* Bh_g = s2th + ((size_t)batch * DD + col0) * (size_t)T2;

    f32x4 acc[4][4];
    #pragma unroll
    for (int i = 0; i < 4; ++i)
        #pragma unroll
        for (int j = 0; j < 4; ++j) acc[i][j] = (f32x4)0.f;

    int nk = (l2v + 31) >> 5;
    ushort4 pAh[4], pBh[4];                 // [rr*2+ss]: u16 lslot*8 + ss*4 (contiguous)
    #pragma unroll
    for (int rr = 0; rr < 2; ++rr)
        #pragma unroll
        for (int ss = 0; ss < 2; ++ss) {
            int q = lrow + rr * 64, s4 = lslot * 8 + ss * 4;
            pAh[rr * 2 + ss] = *(const ushort4*)&Pb[(arow + q) * (size_t)T2 + s4];
            pBh[rr * 2 + ss] = *(const ushort4*)&Bh_g[(size_t)q * T2 + s4];
        }

    for (int kk = 0; kk < nk; ++kk) {
        __syncthreads();
        #pragma unroll
        for (int rr = 0; rr < 2; ++rr)
            #pragma unroll
            for (int ss = 0; ss < 2; ++ss) {
                int o = (lrow + rr * 64) * 40 + lslot * 8 + ss * 4;  // adjacent 8B pair
                *(ushort4*)&sAh[o] = pAh[rr * 2 + ss];
                *(ushort4*)&sBh[o] = pBh[rr * 2 + ss];
            }
        if (kk + 1 < nk) {
            int kn = (kk + 1) * 32;
            #pragma unroll
            for (int rr = 0; rr < 2; ++rr)
                #pragma unroll
                for (int ss = 0; ss < 2; ++ss) {
                    int q = lrow + rr * 64, s4 = kn + lslot * 8 + ss * 4;
                    pAh[rr * 2 + ss] = *(const ushort4*)&Pb[(arow + q) * (size_t)T2 + s4];
                    pBh[rr * 2 + ss] = *(const ushort4*)&Bh_g[(size_t)q * T2 + s4];
                }
        }
        __syncthreads();
        f16x8 ph[4];
        #pragma unroll
        for (int i = 0; i < 4; ++i) {
            int o = (wr + i * 16 + lr) * 40 + lg * 8;
            ph[i] = *(const f16x8*)&sAh[o];
        }
        #pragma unroll
        for (int j = 0; j < 4; ++j) {
            int o = (wc + j * 16 + lr) * 40 + lg * 8;
            f16x8 vh = *(const f16x8*)&sBh[o];
            #pragma unroll
            for (int i = 0; i < 4; ++i)
                acc[i][j] = __builtin_amdgcn_mfma_f32_16x16x32_f16(ph[i], vh, acc[i][j], 0, 0, 0);
        }
    }
    #pragma unroll
    for (int i = 0; i < 4; ++i)
        #pragma unroll
        for (int reg = 0; reg < 4; ++reg) {
            int row = wr + i * 16 + 4 * lg + reg;
            bool valid = (row0 + row) < l1v;
            #pragma unroll
            for (int j = 0; j < 4; ++j)
                Co[(size_t)row * DD + wc + j * 16 + lr] = valid ? acc[i][j][reg] : 0.f;
        }
}

// ======= fallback path kernels (ws < 192 MiB; never exercised on this rig) =======
__global__ __launch_bounds__(256)
void conv_transpose(const float* __restrict__ s2, const int* __restrict__ l2,
                    u16* __restrict__ s2th)
{
    __shared__ float tile[64][65];
    int b = blockIdx.z, j0 = blockIdx.y * 64, d0 = blockIdx.x * 64;
    if (j0 >= l2[b]) return;
    int t = threadIdx.x;
    const float* src = s2 + ((size_t)b * T2 + j0) * DD + d0;
    #pragma unroll
    for (int rr = 0; rr < 4; ++rr) {
        int row = (t >> 4) + rr * 16, c4 = (t & 15) * 4;
        float4 v = *(const float4*)&src[(size_t)row * DD + c4];
        tile[row][c4 + 0] = v.x; tile[row][c4 + 1] = v.y;
        tile[row][c4 + 2] = v.z; tile[row][c4 + 3] = v.w;
    }
    __syncthreads();
    #pragma unroll
    for (int rr = 0; rr < 4; ++rr) {
        int d = (t >> 4) + rr * 16, j4 = (t & 15) * 4;
        ushort4 h;
        h.x = f16b(tile[j4 + 0][d]);
        h.y = f16b(tile[j4 + 1][d]);
        h.z = f16b(tile[j4 + 2][d]);
        h.w = f16b(tile[j4 + 3][d]);
        size_t o = ((size_t)b * DD + d0 + d) * T2 + j0 + j4;
        *(ushort4*)&s2th[o] = h;
    }
}

__global__ __launch_bounds__(256, 2)
void gemm1_qk(const float* __restrict__ s1, const int* __restrict__ l1,
              const float* __restrict__ s2, const int* __restrict__ l2,
              u16* __restrict__ SP)
{
    __shared__ u16 sAh[128 * 40], sBh[128 * 40];

    int idx = (int)blockIdx.x;
    int batch = idx >> 6;
    int rt = (idx >> 3) & 7, ct = idx & 7;
    int row0 = rt * 128, col0 = ct * 128;
    if (row0 >= l1[batch] || col0 >= l2[batch]) return;

    int t = (int)threadIdx.x;
    int lrow = t >> 2, lslot = t & 3;
    int w = t >> 6, lane = t & 63, lr = lane & 15, lg = lane >> 4;
    int wr = (w >> 1) * 64, wc = (w & 1) * 64;

    const float* As = s1 + ((size_t)batch * T1 + row0) * DD;
    const float* Bs = s2 + ((size_t)batch * T2 + col0) * DD;
    u16* Cs = SP + ((size_t)batch * T1 + row0) * (size_t)T2 + col0;

    f32x4 acc[4][4];
    #pragma unroll
    for (int i = 0; i < 4; ++i)
        #pragma unroll
        for (int j = 0; j < 4; ++j) acc[i][j] = (f32x4)0.f;

    float4 pA[4], pB[4];
    #pragma unroll
    for (int rr = 0; rr < 2; ++rr)
        #pragma unroll
        for (int c = 0; c < 2; ++c) {
            pA[rr * 2 + c] = *(const float4*)&As[(size_t)(lrow + rr * 64) * DD + lslot * 8 + c * 4];
            pB[rr * 2 + c] = *(const float4*)&Bs[(size_t)(lrow + rr * 64) * DD + lslot * 8 + c * 4];
        }

    for (int k0 = 0; k0 < DD; k0 += 32) {
        __syncthreads();
        #pragma unroll
        for (int rr = 0; rr < 2; ++rr) {
            int o = (lrow + rr * 64) * 40 + lslot * 8;
            u16x8 h;
            cvtf16x8(pA[rr * 2], pA[rr * 2 + 1], h);
            *(u16x8*)&sAh[o] = h;
            cvtf16x8(pB[rr * 2], pB[rr * 2 + 1], h);
            *(u16x8*)&sBh[o] = h;
        }
        if (k0 + 32 < DD) {
            int kn = k0 + 32;
            #pragma unroll
            for (int rr = 0; rr < 2; ++rr)
                #pragma unroll
                for (int c = 0; c < 2; ++c) {
                    pA[rr * 2 + c] = *(const float4*)&As[(size_t)(lrow + rr * 64) * DD + kn + lslot * 8 + c * 4];
                    pB[rr * 2 + c] = *(const float4*)&Bs[(size_t)(lrow + rr * 64) * DD + kn + lslot * 8 + c * 4];
                }
        }
        __syncthreads();
        f16x8 ah[4];
        #pragma unroll
        for (int i = 0; i < 4; ++i) {
            int o = (wr + i * 16 + lr) * 40 + lg * 8;
            ah[i] = *(const f16x8*)&sAh[o];
        }
        #pragma unroll
        for (int j = 0; j < 4; ++j) {
            int o = (wc + j * 16 + lr) * 40 + lg * 8;
            f16x8 bh = *(const f16x8*)&sBh[o];
            #pragma unroll
            for (int i = 0; i < 4; ++i)
                acc[i][j] = __builtin_amdgcn_mfma_f32_16x16x32_f16(ah[i], bh, acc[i][j], 0, 0, 0);
        }
    }
    #pragma unroll
    for (int i = 0; i < 4; ++i)
        #pragma unroll
        for (int j = 0; j < 4; ++j)
            #pragma unroll
            for (int reg = 0; reg < 4; ++reg)
                Cs[(size_t)(wr + i * 16 + 4 * lg + reg) * T2 + wc + j * 16 + lr] =
                    f16b(acc[i][j][reg]);
}

extern "C" void kernel_launch(void* const* d_in, const int* in_sizes, int n_in,
                              void* d_out, int out_size, void* d_ws, size_t ws_size,
                              hipStream_t stream)
{
    const float* s1 = (const float*)d_in[0];
    const int* l1 = (const int*)d_in[1];
    const float* s2 = (const float*)d_in[2];
    const int* l2 = (const int*)d_in[3];
    float* outp = (float*)d_out;

    int B = in_sizes[1];
    size_t elems = (size_t)B * T2 * DD;
    size_t plane = elems * sizeof(u16);             // 64 MiB @B=32

    if (ws_size >= 3 * plane) {
        // main: fused {gemm1 fp16 K-split + conv}, {softmax | zerofill}, PV
        char* p = (char*)d_ws;
        u16* SPa = (u16*)p;                 p += plane;
        u16* SPb = (u16*)p;                 p += plane;
        u16* s2th = (u16*)p;
        int ng1 = B * 128;
        int ngc = B * 256;                  // (T2/64)*(DD/64) per batch
        int ngs = B * 32;                   // softmax row-tiles
        int ngz = B * 64;                   // output q-tiles (zerofill)
        gemm1_conv<<<dim3(ng1 + ngc), 256, 0, stream>>>(s1, s2, l1, l2, SPa, SPb, s2th, ng1);
        softmax_rows<<<dim3(ngs + ngz), 256, 0, stream>>>(SPa, SPb, 1, l1, l2, outp, ngs);
        gemm2_pv<<<dim3(B * 64), 256, 0, stream>>>(SPa, s2th, l1, l2, outp);
    } else {
        // fallback: full-K fp16 gemm1, separate conv; zerofill rides softmax
        u16* SPa = (u16*)d_ws;
        u16* s2th = SPa + elems;
        int ngs = B * 32, ngz = B * 64;
        conv_transpose<<<dim3(DD / 64, T2 / 64, B), 256, 0, stream>>>(s2, l2, s2th);
        gemm1_qk<<<dim3(B * 64), 256, 0, stream>>>(s1, l1, s2, l2, SPa);
        softmax_rows<<<dim3(ngs + ngz), 256, 0, stream>>>(SPa, SPa, 0, l1, l2, outp, ngs);
        gemm2_pv<<<dim3(B * 64), 256, 0, stream>>>(SPa, s2th, l1, l2, outp);
    }
}

// Round 25
// 219.168 us; speedup vs baseline: 1.0313x; 1.0158x over previous
//
#include <hip/hip_runtime.h>

// biDAF attention: S = s1 s2^T, masked softmax over t2, U = P s2.
// B=32 (from in_sizes), t1=t2=D=1024, fp32 in/out.
//
// FINAL (round 25 = round 24, converged at 222.6 us, 9.3x over baseline).
// Pipeline: 3 dispatches.
//  d1 gemm1_conv: fused {QK^T K-split (fp16 ah*bh, 1 MFMA, fp32 acc,
//     fp16 S-partials out) | s2->s2th transposed fp16 conv backfill}
//  d2 softmax_rows: fused {masked softmax, l2-bounded chunks, P fp16
//     in-place | dead-q-tile zerofill backfill}
//  d3 gemm2_pv: U = Ph*Vh (fp16, 1 MFMA), dead tiles early-return.
// Numeric ledger (measured): fp32-grade 0.031 -> drop b-lo 0.039 ->
// drop a-lo 0.0479 -> fp16 S-partials 0.0840 vs threshold 0.0994.
// Structure ledger: 2-barrier reg-staged 128^2 template beat dbuf x3,
// gload_lds x2, LDS-free, BK=64 (rounds 4-11, 23) -- at 2-5 blocks/CU,
// cross-block wave overlap is the latency hider; extra in-flight state
// costs residency. Latency-bound (HBM 32%, MFMA 6.5%): remaining fusion/
// preconversion ideas are net-negative by dispatch-level byte arithmetic.

typedef __attribute__((ext_vector_type(8))) _Float16 f16x8;
typedef __attribute__((ext_vector_type(8))) unsigned short u16x8;
typedef __attribute__((ext_vector_type(4))) float f32x4;
typedef unsigned short u16;

constexpr int T1 = 1024;
constexpr int T2 = 1024;
constexpr int DD = 1024;
constexpr float NEGV = -1e30f;

__device__ __forceinline__ u16 f16b(float x) {          // fp32 -> fp16 (RN), bits
    union { _Float16 f; u16 u; } cv;
    cv.f = (_Float16)x;
    return cv.u;
}

__device__ __forceinline__ float f16tof(u16 b) {        // fp16 bits -> fp32
    union { _Float16 f; u16 u; } cv;
    cv.u = b;
    return (float)cv.f;
}

__device__ __forceinline__ void cvtf16x8(const float4& a, const float4& b, u16x8& h) {
    h[0] = f16b(a.x); h[1] = f16b(a.y); h[2] = f16b(a.z); h[3] = f16b(a.w);
    h[4] = f16b(b.x); h[5] = f16b(b.y); h[6] = f16b(b.z); h[7] = f16b(b.w);
}

// ---------------- fused k0+k1: gemm1 K-split blocks, then conv backfill ----------------
__global__ __launch_bounds__(256, 2)
void gemm1_conv(const float* __restrict__ s1, const float* __restrict__ s2,
                const int* __restrict__ l1, const int* __restrict__ l2,
                u16* __restrict__ SPa, u16* __restrict__ SPb,
                u16* __restrict__ s2th, int ng1)
{
    __shared__ __align__(16) u16 sBuf[2 * 128 * 40];     // 20 KB, dual-use

    int bid = (int)blockIdx.x;
    if (bid >= ng1) {
        // ======== conv path: s2 -> transposed fp16-RN hi plane ========
        int cid = bid - ng1;
        int b = cid >> 8;
        int j0 = ((cid >> 4) & 15) * 64;
        int d0 = (cid & 15) * 64;
        if (j0 >= l2[b]) return;             // cols never read downstream
        float (*tile)[65] = (float(*)[65])sBuf;          // 16.6 KB < 20 KB
        int t = (int)threadIdx.x;
        const float* src = s2 + ((size_t)b * T2 + j0) * DD + d0;
        #pragma unroll
        for (int rr = 0; rr < 4; ++rr) {
            int row = (t >> 4) + rr * 16, c4 = (t & 15) * 4;
            float4 v = *(const float4*)&src[(size_t)row * DD + c4];
            tile[row][c4 + 0] = v.x; tile[row][c4 + 1] = v.y;
            tile[row][c4 + 2] = v.z; tile[row][c4 + 3] = v.w;
        }
        __syncthreads();
        #pragma unroll
        for (int rr = 0; rr < 4; ++rr) {
            int d = (t >> 4) + rr * 16, j4 = (t & 15) * 4;
            ushort4 h;
            h.x = f16b(tile[j4 + 0][d]);
            h.y = f16b(tile[j4 + 1][d]);
            h.z = f16b(tile[j4 + 2][d]);
            h.w = f16b(tile[j4 + 3][d]);
            size_t o = ((size_t)b * DD + d0 + d) * T2 + j0 + j4;
            *(ushort4*)&s2th[o] = h;
        }
        return;
    }

    // ======== gemm1 path: S = ah*bh (pure fp16, 1 MFMA), K-split, fp16 S-out ========
    u16* sAh = sBuf;
    u16* sBh = sBuf + 128 * 40;

    int idx = bid;
    int batch = idx >> 7;
    int rt = (idx >> 4) & 7, ct = (idx >> 1) & 7, kp = idx & 1;
    int row0 = rt * 128, col0 = ct * 128;
    if (row0 >= l1[batch] || col0 >= l2[batch]) return;

    int t = (int)threadIdx.x;
    int lrow = t >> 2, lslot = t & 3;       // thread covers floats [lslot*8, lslot*8+8)
    int w = t >> 6, lane = t & 63, lr = lane & 15, lg = lane >> 4;
    int wr = (w >> 1) * 64, wc = (w & 1) * 64;

    const float* As = s1 + ((size_t)batch * T1 + row0) * DD + kp * 512;
    const float* Bs = s2 + ((size_t)batch * T2 + col0) * DD + kp * 512;
    u16* SP = kp ? SPb : SPa;
    u16* Cs = SP + ((size_t)batch * T1 + row0) * (size_t)T2 + col0;

    f32x4 acc[4][4];
    #pragma unroll
    for (int i = 0; i < 4; ++i)
        #pragma unroll
        for (int j = 0; j < 4; ++j) acc[i][j] = (f32x4)0.f;

    float4 pA[4], pB[4];                    // [rr*2+c]: floats lslot*8 + c*4 (contiguous)
    #pragma unroll
    for (int rr = 0; rr < 2; ++rr)
        #pragma unroll
        for (int c = 0; c < 2; ++c) {
            pA[rr * 2 + c] = *(const float4*)&As[(size_t)(lrow + rr * 64) * DD + lslot * 8 + c * 4];
            pB[rr * 2 + c] = *(const float4*)&Bs[(size_t)(lrow + rr * 64) * DD + lslot * 8 + c * 4];
        }

    for (int k0 = 0; k0 < 512; k0 += 32) {
        __syncthreads();
        #pragma unroll
        for (int rr = 0; rr < 2; ++rr) {
            int o = (lrow + rr * 64) * 40 + lslot * 8;   // 16B store, 16B-aligned
            u16x8 h;
            cvtf16x8(pA[rr * 2], pA[rr * 2 + 1], h);
            *(u16x8*)&sAh[o] = h;
            cvtf16x8(pB[rr * 2], pB[rr * 2 + 1], h);
            *(u16x8*)&sBh[o] = h;
        }
        if (k0 + 32 < 512) {                 // prefetch next chunk under MFMA
            int kn = k0 + 32;
            #pragma unroll
            for (int rr = 0; rr < 2; ++rr)
                #pragma unroll
                for (int c = 0; c < 2; ++c) {
                    pA[rr * 2 + c] = *(const float4*)&As[(size_t)(lrow + rr * 64) * DD + kn + lslot * 8 + c * 4];
                    pB[rr * 2 + c] = *(const float4*)&Bs[(size_t)(lrow + rr * 64) * DD + kn + lslot * 8 + c * 4];
                }
        }
        __syncthreads();
        f16x8 ah[4];
        #pragma unroll
        for (int i = 0; i < 4; ++i) {
            int o = (wr + i * 16 + lr) * 40 + lg * 8;
            ah[i] = *(const f16x8*)&sAh[o];
        }
        #pragma unroll
        for (int j = 0; j < 4; ++j) {
            int o = (wc + j * 16 + lr) * 40 + lg * 8;
            f16x8 bh = *(const f16x8*)&sBh[o];
            #pragma unroll
            for (int i = 0; i < 4; ++i)
                acc[i][j] = __builtin_amdgcn_mfma_f32_16x16x32_f16(ah[i], bh, acc[i][j], 0, 0, 0);
        }
    }
    #pragma unroll
    for (int i = 0; i < 4; ++i)
        #pragma unroll
        for (int j = 0; j < 4; ++j)
            #pragma unroll
            for (int reg = 0; reg < 4; ++reg)
                Cs[(size_t)(wr + i * 16 + 4 * lg + reg) * T2 + wc + j * 16 + lr] =
                    f16b(acc[i][j][reg]);
}

// ------- k2: masked softmax (fp16 S-in, l2-bounded) | dead-tile zerofill -------
__global__ __launch_bounds__(256)
void softmax_rows(u16* __restrict__ SPa, const u16* __restrict__ SPb,
                  int dual, const int* __restrict__ l1, const int* __restrict__ l2,
                  float* __restrict__ out, int ngs)
{
    int bid = (int)blockIdx.x;
    if (bid >= ngs) {
        // ======== zerofill path: dead output q-tiles (row0 >= l1) ========
        int zid = bid - ngs;
        int b = zid >> 6;
        int rt = (zid >> 3) & 7, ct = zid & 7;
        int row0 = rt * 128;
        if (row0 < l1[b]) return;            // live tile: gemm2 writes it
        float* Co = out + ((size_t)b * T1 + row0) * (size_t)DD + ct * 128;
        int t = (int)threadIdx.x;
        float4 z = make_float4(0.f, 0.f, 0.f, 0.f);
        #pragma unroll
        for (int rr = 0; rr < 2; ++rr) {
            int row = (t >> 2) + rr * 64;
            #pragma unroll
            for (int ss = 0; ss < 8; ++ss)
                *(float4*)&Co[(size_t)row * DD + ((t & 3) + ss * 4) * 4] = z;
        }
        return;
    }

    int batch = bid >> 5;
    int row0 = (bid & 31) * 32;
    int l1v = l1[batch], l2v = l2[batch];
    if (row0 >= l1v) return;
    int w = (int)threadIdx.x >> 6, lane = (int)threadIdx.x & 63;

    for (int i = 0; i < 8; ++i) {
        int r = row0 + w * 8 + i;
        if (r >= l1v) continue;                    // wave-uniform
        size_t roff = ((size_t)batch * T1 + r) * (size_t)T2;   // u16 units
        u16* rowa = SPa + roff;
        const u16* rowb = SPb + roff;
        float x[16];
        float m = NEGV;
        #pragma unroll
        for (int s = 0; s < 4; ++s) {
            if (s * 256 < l2v) {                   // wave-uniform: skip masked chunks
                ushort4 va = *(const ushort4*)&rowa[s * 256 + lane * 4];
                float xs[4] = {f16tof(va.x), f16tof(va.y), f16tof(va.z), f16tof(va.w)};
                if (dual) {
                    ushort4 vb = *(const ushort4*)&rowb[s * 256 + lane * 4];
                    xs[0] += f16tof(vb.x); xs[1] += f16tof(vb.y);
                    xs[2] += f16tof(vb.z); xs[3] += f16tof(vb.w);
                }
                #pragma unroll
                for (int e = 0; e < 4; ++e) {
                    int j = s * 256 + lane * 4 + e;
                    float val = (j < l2v) ? xs[e] : NEGV;
                    x[s * 4 + e] = val;
                    m = fmaxf(m, val);
                }
            }
        }
        #pragma unroll
        for (int off = 32; off >= 1; off >>= 1) m = fmaxf(m, __shfl_xor(m, off));
        float sum = 0.f;
        #pragma unroll
        for (int s = 0; s < 4; ++s) {
            if (s * 256 < l2v) {
                #pragma unroll
                for (int e = 0; e < 4; ++e) {
                    float ev = __expf(x[s * 4 + e] - m);   // masked -> exp(-huge)=0
                    x[s * 4 + e] = ev;
                    sum += ev;
                }
            }
        }
        #pragma unroll
        for (int off = 32; off >= 1; off >>= 1) sum += __shfl_xor(sum, off);
        float inv = 1.f / sum;                     // l2>=1 -> sum>=1
        #pragma unroll
        for (int s = 0; s < 4; ++s) {
            if (s * 256 < l2v) {                   // chunks beyond never read by gemm2
                ushort4 h;
                h.x = f16b(x[s * 4 + 0] * inv);
                h.y = f16b(x[s * 4 + 1] * inv);
                h.z = f16b(x[s * 4 + 2] * inv);
                h.w = f16b(x[s * 4 + 3] * inv);
                *(ushort4*)&rowa[s * 256 + lane * 4] = h;  // P in place
            }
        }
    }
}

// ---------------- k3: U = Ph x Vh (fp16, 1 MFMA; dead tiles pre-zeroed) ----------------
__global__ __launch_bounds__(256, 2)
void gemm2_pv(const u16* __restrict__ SP, const u16* __restrict__ s2th,
              const int* __restrict__ l1, const int* __restrict__ l2,
              float* __restrict__ out)
{
    __shared__ u16 sAh[128 * 40], sBh[128 * 40];

    int idx = (int)blockIdx.x;              // natural order
    int batch = idx >> 6;
    int rt = (idx >> 3) & 7, ct = idx & 7;
    int row0 = rt * 128, col0 = ct * 128;   // q-rows, d-cols
    int l1v = l1[batch], l2v = l2[batch];
    if (row0 >= l1v) return;                // dead tile: zero-filled in dispatch 2

    int t = (int)threadIdx.x;
    float* Co = out + ((size_t)batch * T1 + row0) * (size_t)DD + col0;

    int lrow = t >> 2, lslot = t & 3;       // thread covers u16 [lslot*8, lslot*8+8)
    int w = t >> 6, lane = t & 63, lr = lane & 15, lg = lane >> 4;
    int wr = (w >> 1) * 64, wc = (w & 1) * 64;

    const u16* Pb = SP;                     // P row q at q*1024 (u16 plane)
    size_t arow = ((size_t)batch * T1 + row0);
    const u16* Bh_g = s2th + ((size_t)batch * DD + col0) * (size_t)T2;

    f32x4 acc[4][4];
    #pragma unroll
    for (int i = 0; i < 4; ++i)
        #pragma unroll
        for (int j = 0; j < 4; ++j) acc[i][j] = (f32x4)0.f;

    int nk = (l2v + 31) >> 5;
    ushort4 pAh[4], pBh[4];                 // [rr*2+ss]: u16 lslot*8 + ss*4 (contiguous)
    #pragma unroll
    for (int rr = 0; rr < 2; ++rr)
        #pragma unroll
        for (int ss = 0; ss < 2; ++ss) {
            int q = lrow + rr * 64, s4 = lslot * 8 + ss * 4;
            pAh[rr * 2 + ss] = *(const ushort4*)&Pb[(arow + q) * (size_t)T2 + s4];
            pBh[rr * 2 + ss] = *(const ushort4*)&Bh_g[(size_t)q * T2 + s4];
        }

    for (int kk = 0; kk < nk; ++kk) {
        __syncthreads();
        #pragma unroll
        for (int rr = 0; rr < 2; ++rr)
            #pragma unroll
            for (int ss = 0; ss < 2; ++ss) {
                int o = (lrow + rr * 64) * 40 + lslot * 8 + ss * 4;  // adjacent 8B pair
                *(ushort4*)&sAh[o] = pAh[rr * 2 + ss];
                *(ushort4*)&sBh[o] = pBh[rr * 2 + ss];
            }
        if (kk + 1 < nk) {
            int kn = (kk + 1) * 32;
            #pragma unroll
            for (int rr = 0; rr < 2; ++rr)
                #pragma unroll
                for (int ss = 0; ss < 2; ++ss) {
                    int q = lrow + rr * 64, s4 = kn + lslot * 8 + ss * 4;
                    pAh[rr * 2 + ss] = *(const ushort4*)&Pb[(arow + q) * (size_t)T2 + s4];
                    pBh[rr * 2 + ss] = *(const ushort4*)&Bh_g[(size_t)q * T2 + s4];
                }
        }
        __syncthreads();
        f16x8 ph[4];
        #pragma unroll
        for (int i = 0; i < 4; ++i) {
            int o = (wr + i * 16 + lr) * 40 + lg * 8;
            ph[i] = *(const f16x8*)&sAh[o];
        }
        #pragma unroll
        for (int j = 0; j < 4; ++j) {
            int o = (wc + j * 16 + lr) * 40 + lg * 8;
            f16x8 vh = *(const f16x8*)&sBh[o];
            #pragma unroll
            for (int i = 0; i < 4; ++i)
                acc[i][j] = __builtin_amdgcn_mfma_f32_16x16x32_f16(ph[i], vh, acc[i][j], 0, 0, 0);
        }
    }
    #pragma unroll
    for (int i = 0; i < 4; ++i)
        #pragma unroll
        for (int reg = 0; reg < 4; ++reg) {
            int row = wr + i * 16 + 4 * lg + reg;
            bool valid = (row0 + row) < l1v;
            #pragma unroll
            for (int j = 0; j < 4; ++j)
                Co[(size_t)row * DD + wc + j * 16 + lr] = valid ? acc[i][j][reg] : 0.f;
        }
}

// ======= fallback path kernels (ws < 192 MiB; never exercised on this rig) =======
__global__ __launch_bounds__(256)
void conv_transpose(const float* __restrict__ s2, const int* __restrict__ l2,
                    u16* __restrict__ s2th)
{
    __shared__ float tile[64][65];
    int b = blockIdx.z, j0 = blockIdx.y * 64, d0 = blockIdx.x * 64;
    if (j0 >= l2[b]) return;
    int t = threadIdx.x;
    const float* src = s2 + ((size_t)b * T2 + j0) * DD + d0;
    #pragma unroll
    for (int rr = 0; rr < 4; ++rr) {
        int row = (t >> 4) + rr * 16, c4 = (t & 15) * 4;
        float4 v = *(const float4*)&src[(size_t)row * DD + c4];
        tile[row][c4 + 0] = v.x; tile[row][c4 + 1] = v.y;
        tile[row][c4 + 2] = v.z; tile[row][c4 + 3] = v.w;
    }
    __syncthreads();
    #pragma unroll
    for (int rr = 0; rr < 4; ++rr) {
        int d = (t >> 4) + rr * 16, j4 = (t & 15) * 4;
        ushort4 h;
        h.x = f16b(tile[j4 + 0][d]);
        h.y = f16b(tile[j4 + 1][d]);
        h.z = f16b(tile[j4 + 2][d]);
        h.w = f16b(tile[j4 + 3][d]);
        size_t o = ((size_t)b * DD + d0 + d) * T2 + j0 + j4;
        *(ushort4*)&s2th[o] = h;
    }
}

__global__ __launch_bounds__(256, 2)
void gemm1_qk(const float* __restrict__ s1, const int* __restrict__ l1,
              const float* __restrict__ s2, const int* __restrict__ l2,
              u16* __restrict__ SP)
{
    __shared__ u16 sAh[128 * 40], sBh[128 * 40];

    int idx = (int)blockIdx.x;
    int batch = idx >> 6;
    int rt = (idx >> 3) & 7, ct = idx & 7;
    int row0 = rt * 128, col0 = ct * 128;
    if (row0 >= l1[batch] || col0 >= l2[batch]) return;

    int t = (int)threadIdx.x;
    int lrow = t >> 2, lslot = t & 3;
    int w = t >> 6, lane = t & 63, lr = lane & 15, lg = lane >> 4;
    int wr = (w >> 1) * 64, wc = (w & 1) * 64;

    const float* As = s1 + ((size_t)batch * T1 + row0) * DD;
    const float* Bs = s2 + ((size_t)batch * T2 + col0) * DD;
    u16* Cs = SP + ((size_t)batch * T1 + row0) * (size_t)T2 + col0;

    f32x4 acc[4][4];
    #pragma unroll
    for (int i = 0; i < 4; ++i)
        #pragma unroll
        for (int j = 0; j < 4; ++j) acc[i][j] = (f32x4)0.f;

    float4 pA[4], pB[4];
    #pragma unroll
    for (int rr = 0; rr < 2; ++rr)
        #pragma unroll
        for (int c = 0; c < 2; ++c) {
            pA[rr * 2 + c] = *(const float4*)&As[(size_t)(lrow + rr * 64) * DD + lslot * 8 + c * 4];
            pB[rr * 2 + c] = *(const float4*)&Bs[(size_t)(lrow + rr * 64) * DD + lslot * 8 + c * 4];
        }

    for (int k0 = 0; k0 < DD; k0 += 32) {
        __syncthreads();
        #pragma unroll
        for (int rr = 0; rr < 2; ++rr) {
            int o = (lrow + rr * 64) * 40 + lslot * 8;
            u16x8 h;
            cvtf16x8(pA[rr * 2], pA[rr * 2 + 1], h);
            *(u16x8*)&sAh[o] = h;
            cvtf16x8(pB[rr * 2], pB[rr * 2 + 1], h);
            *(u16x8*)&sBh[o] = h;
        }
        if (k0 + 32 < DD) {
            int kn = k0 + 32;
            #pragma unroll
            for (int rr = 0; rr < 2; ++rr)
                #pragma unroll
                for (int c = 0; c < 2; ++c) {
                    pA[rr * 2 + c] = *(const float4*)&As[(size_t)(lrow + rr * 64) * DD + kn + lslot * 8 + c * 4];
                    pB[rr * 2 + c] = *(const float4*)&Bs[(size_t)(lrow + rr * 64) * DD + kn + lslot * 8 + c * 4];
                }
        }
        __syncthreads();
        f16x8 ah[4];
        #pragma unroll
        for (int i = 0; i < 4; ++i) {
            int o = (wr + i * 16 + lr) * 40 + lg * 8;
            ah[i] = *(const f16x8*)&sAh[o];
        }
        #pragma unroll
        for (int j = 0; j < 4; ++j) {
            int o = (wc + j * 16 + lr) * 40 + lg * 8;
            f16x8 bh = *(const f16x8*)&sBh[o];
            #pragma unroll
            for (int i = 0; i < 4; ++i)
                acc[i][j] = __builtin_amdgcn_mfma_f32_16x16x32_f16(ah[i], bh, acc[i][j], 0, 0, 0);
        }
    }
    #pragma unroll
    for (int i = 0; i < 4; ++i)
        #pragma unroll
        for (int j = 0; j < 4; ++j)
            #pragma unroll
            for (int reg = 0; reg < 4; ++reg)
                Cs[(size_t)(wr + i * 16 + 4 * lg + reg) * T2 + wc + j * 16 + lr] =
                    f16b(acc[i][j][reg]);
}

extern "C" void kernel_launch(void* const* d_in, const int* in_sizes, int n_in,
                              void* d_out, int out_size, void* d_ws, size_t ws_size,
                              hipStream_t stream)
{
    const float* s1 = (const float*)d_in[0];
    const int* l1 = (const int*)d_in[1];
    const float* s2 = (const float*)d_in[2];
    const int* l2 = (const int*)d_in[3];
    float* outp = (float*)d_out;

    int B = in_sizes[1];
    size_t elems = (size_t)B * T2 * DD;
    size_t plane = elems * sizeof(u16);             // 64 MiB @B=32

    if (ws_size >= 3 * plane) {
        // main: fused {gemm1 fp16 K-split + conv}, {softmax | zerofill}, PV
        char* p = (char*)d_ws;
        u16* SPa = (u16*)p;                 p += plane;
        u16* SPb = (u16*)p;                 p += plane;
        u16* s2th = (u16*)p;
        int ng1 = B * 128;
        int ngc = B * 256;                  // (T2/64)*(DD/64) per batch
        int ngs = B * 32;                   // softmax row-tiles
        int ngz = B * 64;                   // output q-tiles (zerofill)
        gemm1_conv<<<dim3(ng1 + ngc), 256, 0, stream>>>(s1, s2, l1, l2, SPa, SPb, s2th, ng1);
        softmax_rows<<<dim3(ngs + ngz), 256, 0, stream>>>(SPa, SPb, 1, l1, l2, outp, ngs);
        gemm2_pv<<<dim3(B * 64), 256, 0, stream>>>(SPa, s2th, l1, l2, outp);
    } else {
        // fallback: full-K fp16 gemm1, separate conv; zerofill rides softmax
        u16* SPa = (u16*)d_ws;
        u16* s2th = SPa + elems;
        int ngs = B * 32, ngz = B * 64;
        conv_transpose<<<dim3(DD / 64, T2 / 64, B), 256, 0, stream>>>(s2, l2, s2th);
        gemm1_qk<<<dim3(B * 64), 256, 0, stream>>>(s1, l1, s2, l2, SPa);
        softmax_rows<<<dim3(ngs + ngz), 256, 0, stream>>>(SPa, SPa, 0, l1, l2, outp, ngs);
        gemm2_pv<<<dim3(B * 64), 256, 0, stream>>>(SPa, s2th, l1, l2, outp);
    }
}